// Round 1
// baseline (227.894 us; speedup 1.0000x reference)
//
#include <hip/hip_runtime.h>

// SplineFilter: out[b,n,f] = eval_x[b,n,f] * sf^2,
//   sf = sum_k basis_k(eigs[b,n]) * coeffs[k,f]
// Cubic B-spline over uniform knots linspace(0,2,16), 12 bases; only 4
// nonzero taps per x (cardinal cubic weights in t = x*7.5 - i).
//
// Memory-bound (269.5 MB min traffic -> ~43 us @ 6.3 TB/s). This version:
// - EXACT template: grid covers total4 exactly (host-verified) -> zero
//   bounds branches, so the 4 chunk bodies are branch-free straight-line
//   code the scheduler can fully interleave (cross-chunk ILP).
// - Zero-padded LDS table (18 rows, k=-3..14, 9 KB): taps are
//   unconditional ds_read_b128 at compile-time offsets; the per-tap
//   min/max/cmp/cndmask chain is gone. One clamp on i + one on tt also
//   makes OOB x produce sf=0 (matches reference semantics).
// - eigs loads issued BEFORE x loads: the weight chain (the long
//   dependency) starts as early as possible; x is only needed at the
//   final multiply.
// - Non-temporal load/store on the streamed arrays (no reuse; working
//   set 269 MB > 256 MB L3, NT avoids thrash).

#define N_BASES 12
#define F_CH 128
#define CHUNKS 4
#define PAD 3
#define TAB_ROWS (N_BASES + 2 * PAD)  // 18 rows: k = -3..14
#define ROW_VF4 (F_CH / 4)            // 32 vf4 per row

typedef float vf4 __attribute__((ext_vector_type(4)));

template <bool EXACT>
__global__ __launch_bounds__(256) void spline_filter_kernel(
    const vf4* __restrict__ x4,      // eval_x as vf4
    const float* __restrict__ eigs,  // [rows]
    const vf4* __restrict__ coeffs4, // [12*32]
    vf4*       __restrict__ out4,
    int total4, int stride4)
{
    __shared__ vf4 sc[TAB_ROWS * ROW_VF4];  // 9 KB, zero-padded

    const int t = threadIdx.x;
    for (int r = t; r < TAB_ROWS * ROW_VF4; r += 256) {
        const int k = (r >> 5) - PAD;
        sc[r] = ((unsigned)k < (unsigned)N_BASES)
                    ? coeffs4[k * ROW_VF4 + (r & 31)]
                    : (vf4)0.0f;
    }
    __syncthreads();

    const int gid = blockIdx.x * 256 + t;

    float eg[CHUNKS];
    vf4   xv[CHUNKS];

    // Issue the loads the long dependency chain needs FIRST.
    #pragma unroll
    for (int c = 0; c < CHUNKS; ++c) {
        const int idx = gid + c * stride4;
        if (EXACT || idx < total4) eg[c] = eigs[idx >> 5];
        else                       eg[c] = 0.0f;
    }
    #pragma unroll
    for (int c = 0; c < CHUNKS; ++c) {
        const int idx = gid + c * stride4;
        if (EXACT || idx < total4) xv[c] = __builtin_nontemporal_load(&x4[idx]);
        else                       xv[c] = (vf4)0.0f;
    }

    // stride4 is a multiple of 32, so lane is chunk-invariant.
    const int lane = gid & 31;

    #pragma unroll
    for (int c = 0; c < CHUNKS; ++c) {
        const int idx = gid + c * stride4;
        if (!EXACT && idx >= total4) continue;

        // 4 nonzero cardinal cubic weights for x = eg[c]
        const float u = eg[c] * 7.5f;          // x / (2/15)
        int i = (int)u;
        i = min(max(i, 0), N_BASES + 2);       // rows i..i+3 stay in-table
        float tt = u - (float)i;
        tt = fminf(fmaxf(tt, 0.0f), 1.0f);     // OOB x -> all taps hit zero rows
        const float t2  = tt * tt;
        const float t3  = t2 * tt;
        const float omt = 1.0f - tt;
        const float w0 = omt * omt * omt * (1.0f / 6.0f);                        // k=i-3
        const float w1 = (3.0f * t3 - 6.0f * t2 + 4.0f) * (1.0f / 6.0f);         // k=i-2
        const float w2 = (-3.0f * t3 + 3.0f * t2 + 3.0f * tt + 1.0f) * (1.0f / 6.0f); // k=i-1
        const float w3 = t3 * (1.0f / 6.0f);                                     // k=i

        // Table row for tap j is (k+PAD) = i+j -> base + compile-time offsets.
        const vf4* row = &sc[i * ROW_VF4 + lane];
        vf4 sf = w0 * row[0]
               + w1 * row[ROW_VF4]
               + w2 * row[2 * ROW_VF4]
               + w3 * row[3 * ROW_VF4];

        const vf4 o = xv[c] * sf * sf;
        __builtin_nontemporal_store(o, &out4[idx]);
    }
}

extern "C" void kernel_launch(void* const* d_in, const int* in_sizes, int n_in,
                              void* d_out, int out_size, void* d_ws, size_t ws_size,
                              hipStream_t stream) {
    const float* eval_x = (const float*)d_in[0];  // [32,8192,128] fp32
    const float* eigs   = (const float*)d_in[1];  // [32,8192]     fp32
    const float* coeffs = (const float*)d_in[2];  // [12,128]      fp32
    float* out = (float*)d_out;

    const int total4  = in_sizes[0] / 4;                               // 8388608
    const int blocks  = (total4 + 256 * CHUNKS - 1) / (256 * CHUNKS);  // 8192
    const int stride4 = blocks * 256;
    const bool exact  = (blocks * 256 * CHUNKS == total4);

    if (exact) {
        spline_filter_kernel<true><<<blocks, 256, 0, stream>>>(
            (const vf4*)eval_x, eigs, (const vf4*)coeffs, (vf4*)out,
            total4, stride4);
    } else {
        spline_filter_kernel<false><<<blocks, 256, 0, stream>>>(
            (const vf4*)eval_x, eigs, (const vf4*)coeffs, (vf4*)out,
            total4, stride4);
    }
}